// Round 2
// baseline (709.461 us; speedup 1.0000x reference)
//
#include <hip/hip_runtime.h>

#define NB 512
#define NC 32
#define NT 8192
#define TP 1024        // NT / 8 pooled windows
#define NG 11
#define WIN 256        // pooled windows per block (2048 time samples)
#define NTB (TP/WIN)   // 4 time-tiles per batch

typedef float f32x4 __attribute__((ext_vector_type(4)));

// One channel: 8 KB of x (nt) + 8 KB of W, 16 independent dwordx4 loads issued
// back-to-back BEFORE any consuming VALU -> deep MLP per wave.
// Lane i, slot k accumulates the quad-pair of window 64k+i.
template<int C>
__device__ __forceinline__ void do_ch(const float* __restrict__ xb,
                                      const float* __restrict__ Wb,
                                      const float* __restrict__ bias,
                                      float (&acc)[4])
{
    f32x4 xv[8], wv[8];
    #pragma unroll
    for (int k = 0; k < 4; ++k) {
        xv[2*k]   = __builtin_nontemporal_load((const f32x4*)(xb + C*NT + 512*k));
        xv[2*k+1] = __builtin_nontemporal_load((const f32x4*)(xb + C*NT + 512*k + 4));
    }
    #pragma unroll
    for (int k = 0; k < 4; ++k) {
        wv[2*k]   = *(const f32x4*)(Wb + C*NT + 512*k);
        wv[2*k+1] = *(const f32x4*)(Wb + C*NT + 512*k + 4);
    }
    const float nbc = -bias[C];
    #pragma unroll
    for (int k = 0; k < 4; ++k) {
        const f32x4 a0 = xv[2*k], a1 = xv[2*k+1];
        const f32x4 b0 = wv[2*k], b1 = wv[2*k+1];
        float s;
        s  = fmaxf(fmaf(a0.x, b0.x, nbc), 0.0f);
        s += fmaxf(fmaf(a0.y, b0.y, nbc), 0.0f);
        s += fmaxf(fmaf(a0.z, b0.z, nbc), 0.0f);
        s += fmaxf(fmaf(a0.w, b0.w, nbc), 0.0f);
        s += fmaxf(fmaf(a1.x, b1.x, nbc), 0.0f);
        s += fmaxf(fmaf(a1.y, b1.y, nbc), 0.0f);
        s += fmaxf(fmaf(a1.z, b1.z, nbc), 0.0f);
        s += fmaxf(fmaf(a1.w, b1.w, nbc), 0.0f);
        acc[k] += s;
    }
}

__device__ __forceinline__ void store_g(float* __restrict__ ob, int gid,
                                        float inv, const float (&acc)[4], int lane)
{
    #pragma unroll
    for (int k = 0; k < 4; ++k)
        __builtin_nontemporal_store(acc[k] * inv, ob + (size_t)gid * TP + 64*k + lane);
}

__global__ __launch_bounds__(256, 4) void local_gnn_kernel(
    const float* __restrict__ xg,
    const float* __restrict__ W,
    const float* __restrict__ bias,
    float* __restrict__ out)
{
    const int lane = threadIdx.x & 63;
    const int y    = threadIdx.x >> 6;   // wave id — wave-uniform
    const int bb   = blockIdx.x >> 2;    // batch
    const int tb   = blockIdx.x & 3;     // time-tile

    const float* xb = xg + (size_t)bb * (NC * NT) + tb * (WIN * 8) + 8 * lane;
    const float* Wb = W + tb * (WIN * 8) + 8 * lane;

    // acc[lg][k]: local group lg (<=3 per wave), window 64k+lane of this tile
    float acc[3][4];
    #pragma unroll
    for (int lg = 0; lg < 3; ++lg)
        #pragma unroll
        for (int k = 0; k < 4; ++k) acc[lg][k] = 0.0f;

    float* ob = out + (size_t)bb * (NG * TP) + tb * WIN;

    // Each wave owns WHOLE groups -> no cross-wave reduction, no LDS, no barrier.
    // Channel counts per wave: 7 / 7 / 7 / 8.
    switch (y) {
    case 0:  // g0:{0,1}  g1:{3,2}  g6:{6,23,24}
        do_ch<0>(xb, Wb, bias, acc[0]);  do_ch<1>(xb, Wb, bias, acc[0]);
        do_ch<2>(xb, Wb, bias, acc[1]);  do_ch<3>(xb, Wb, bias, acc[1]);
        do_ch<6>(xb, Wb, bias, acc[2]);  do_ch<23>(xb, Wb, bias, acc[2]);
        do_ch<24>(xb, Wb, bias, acc[2]);
        store_g(ob, 0, 1.f/16, acc[0], lane);
        store_g(ob, 1, 1.f/16, acc[1], lane);
        store_g(ob, 6, 1.f/24, acc[2], lane);
        break;
    case 1:  // g2:{4,5}  g7:{8,9,27}  g9:{12,30}
        do_ch<4>(xb, Wb, bias, acc[0]);  do_ch<5>(xb, Wb, bias, acc[0]);
        do_ch<8>(xb, Wb, bias, acc[1]);  do_ch<9>(xb, Wb, bias, acc[1]);
        do_ch<27>(xb, Wb, bias, acc[1]);
        do_ch<12>(xb, Wb, bias, acc[2]); do_ch<30>(xb, Wb, bias, acc[2]);
        store_g(ob, 2, 1.f/16, acc[0], lane);
        store_g(ob, 7, 1.f/24, acc[1], lane);
        store_g(ob, 9, 1.f/16, acc[2], lane);
        break;
    case 2:  // g3:{16,17}  g4:{19,20}  g10:{13,14,31}
        do_ch<16>(xb, Wb, bias, acc[0]); do_ch<17>(xb, Wb, bias, acc[0]);
        do_ch<19>(xb, Wb, bias, acc[1]); do_ch<20>(xb, Wb, bias, acc[1]);
        do_ch<13>(xb, Wb, bias, acc[2]); do_ch<14>(xb, Wb, bias, acc[2]);
        do_ch<31>(xb, Wb, bias, acc[2]);
        store_g(ob, 3, 1.f/16, acc[0], lane);
        store_g(ob, 4, 1.f/16, acc[1], lane);
        store_g(ob, 10, 1.f/24, acc[2], lane);
        break;
    default: // g5:{22,21}  g8:{11,10,15,28,26,29}
        do_ch<21>(xb, Wb, bias, acc[0]); do_ch<22>(xb, Wb, bias, acc[0]);
        do_ch<10>(xb, Wb, bias, acc[1]); do_ch<11>(xb, Wb, bias, acc[1]);
        do_ch<15>(xb, Wb, bias, acc[1]); do_ch<26>(xb, Wb, bias, acc[1]);
        do_ch<28>(xb, Wb, bias, acc[1]); do_ch<29>(xb, Wb, bias, acc[1]);
        store_g(ob, 5, 1.f/16, acc[0], lane);
        store_g(ob, 8, 1.f/48, acc[1], lane);
        break;
    }
}

extern "C" void kernel_launch(void* const* d_in, const int* in_sizes, int n_in,
                              void* d_out, int out_size, void* d_ws, size_t ws_size,
                              hipStream_t stream) {
    const float* x    = (const float*)d_in[0];
    const float* W    = (const float*)d_in[1];
    const float* bias = (const float*)d_in[2];
    float* out        = (float*)d_out;

    const int grid = NB * NTB;   // 512 * 4 = 2048 blocks
    hipLaunchKernelGGL(local_gnn_kernel, dim3(grid), dim3(256), 0, stream,
                       x, W, bias, out);
}